// Round 14
// baseline (271.533 us; speedup 1.0000x reference)
//
#include <hip/hip_runtime.h>

typedef __attribute__((ext_vector_type(4))) float f32x4;
typedef __attribute__((ext_vector_type(8))) short s16x8;
typedef __attribute__((ext_vector_type(4))) unsigned int u32x4;

#define HW 112
#define ROWS8 (116*8)             // shorts per (plane,row) = 928 (116 slots x 8c)
#define PLANE8 (112*ROWS8)        // shorts per (n,oct) plane = 103,936
#define CHW (64*112*112)          // 802816
#define X_ELEMS 25690112

// ws byte offsets (kept from r8-r13; conv over-reads <=112B past xq8 -> 4KB slack)
#define WT_OFF    53219328
#define ZP_OFF    59001984

__device__ __forceinline__ unsigned short f32_to_bf16_exact(float q) {
    return (unsigned short)(__float_as_uint(q) >> 16);
}
__device__ __forceinline__ unsigned int pack_bf16x2(float a, float b) {
    return __builtin_amdgcn_perm(__float_as_uint(b), __float_as_uint(a), 0x07060302u);
}
__device__ __forceinline__ void scale_from_max(float m, float& scale, float& inv) {
    if (m > 0.f) {
        int e = (int)((__float_as_uint(m) >> 23) & 0xFF) - 127;
        scale = __builtin_ldexpf(1.0f, e - 7);
        inv   = __builtin_ldexpf(1.0f, 7 - e);
    } else { scale = 0.f; inv = 0.f; }
}

// ---- QX: ONE pass over x (r10-r13 structure, unchanged). Blocks 7168-7171
// run the weight path instead (saves a launch); block 7168 also zeroes zp. ----
__global__ __launch_bounds__(256) void qx_fused(const float* __restrict__ x,
                                                const float* __restrict__ w,
                                                unsigned short* __restrict__ xq8,
                                                unsigned short* __restrict__ wt,
                                                u32x4* __restrict__ zp) {
    __shared__ float vals[8 * 448];               // f32 values, this chunk, 8 channels
    __shared__ float lmax[1024];                  // 8 ch x 128 grains (112 + 2x8 halo)
    __shared__ float2 ssc[8][16];                 // per-channel group (s, inv)
    __shared__ int sgs[8];                        // per-channel first group id
    const int tid = threadIdx.x;
    const int b = blockIdx.x;

    if (b >= 7168) {                              // ---- weight path: 1024 groups of 36
        if (b == 7168 && tid < 64) zp[tid] = (u32x4){0u, 0u, 0u, 0u};
        int g = (b - 7168) * 256 + tid;
        const float4* p = (const float4*)w + g * 9;
        float vv[36]; float m = 0.f;
        #pragma unroll
        for (int i = 0; i < 9; ++i) {
            float4 v = p[i];
            vv[i*4+0]=v.x; vv[i*4+1]=v.y; vv[i*4+2]=v.z; vv[i*4+3]=v.w;
            m = fmaxf(m, fmaxf(fmaxf(fabsf(v.x), fabsf(v.y)), fmaxf(fabsf(v.z), fabsf(v.w))));
        }
        float s, inv; scale_from_max(m, s, inv);
        #pragma unroll
        for (int j = 0; j < 36; ++j) {
            int flat = g * 36 + j;
            int k = flat / 576, rem = flat % 576;
            int c = rem / 9, pp = rem % 9;
            float q = rintf(vv[j] * inv) * s;
            wt[pp * 4096 + k * 64 + c] = f32_to_bf16_exact(q);
        }
        return;
    }

    const int plane = b / 28, chunk = b - plane * 28;
    const int p0 = chunk * 448;
    const int base_plane = plane * 8 * 12544;     // flat base of channel oct*8 of image n

    #pragma unroll
    for (int it = 0; it < 4; ++it) {
        int g = it * 256 + tid;
        int j = g >> 7, gi = g & 127;
        int flat = base_plane + j * 12544 + p0 - 32 + gi * 4;
        float4 v = {0.f, 0.f, 0.f, 0.f};
        if (flat >= 0 && flat < X_ELEMS) v = *(const float4*)(x + flat);  // 16B aligned
        lmax[g] = fmaxf(fmaxf(fabsf(v.x), fabsf(v.y)), fmaxf(fabsf(v.z), fabsf(v.w)));
        if (gi >= 8 && gi < 120)
            *(f32x4*)&vals[j * 448 + (gi - 8) * 4] = (f32x4){v.x, v.y, v.z, v.w};
    }
    __syncthreads();

    if (tid < 128) {
        int j = tid >> 4, k = tid & 15;
        unsigned a0 = (unsigned)(base_plane + j * 12544 + p0);
        int gstart = (int)(a0 / 36u);
        int gend   = (int)((a0 + 447u) / 36u);
        if (k == 0) sgs[j] = gstart;
        if (gstart + k <= gend) {
            int ps = 36 * (gstart + k) - (int)a0;  // group start rel. p0, in [-32, 444], 4-aligned
            int gb = ps / 4 + 8;                   // first grain index in lmax[j][.]
            float m = 0.f;
            #pragma unroll
            for (int q = 0; q < 9; ++q) m = fmaxf(m, lmax[j * 128 + gb + q]);
            float s, inv; scale_from_max(m, s, inv);
            ssc[j][k] = make_float2(s, inv);
        }
    }
    __syncthreads();

    const int hrow0 = chunk * 4;
    #pragma unroll
    for (int it = 0; it < 2; ++it) {
        int s = it * 256 + tid;
        if (s < 464) {                            // 4 rows x 116 slots (incl. pads)
            int h = s / 116, w2 = s - h * 116;
            unsigned short* dst = xq8 + (plane * 112 + hrow0 + h) * ROWS8 + w2 * 8;
            u32x4 o = {0u, 0u, 0u, 0u};
            if (w2 >= 2 && w2 < 114) {
                int dp = h * 112 + (w2 - 2);
                unsigned pbase = (unsigned)(base_plane + p0 + dp);
                float qv[8];
                #pragma unroll
                for (int j = 0; j < 8; ++j) {
                    float v = vals[j * 448 + dp];
                    unsigned g = (pbase + (unsigned)j * 12544u) / 36u;
                    float2 sv = ssc[j][(int)g - sgs[j]];
                    qv[j] = rintf(v * sv.y) * sv.x;
                }
                o.x = pack_bf16x2(qv[0], qv[1]);
                o.y = pack_bf16x2(qv[2], qv[3]);
                o.z = pack_bf16x2(qv[4], qv[5]);
                o.w = pack_bf16x2(qv[6], qv[7]);
            }
            *(u32x4*)dst = o;                     // coalesced 16B/lane
        }
    }
}

// ---- conv: r10 schedule (dbuf, grid 256 persistent, vmcnt(0); r11 vmcnt(14)
// and r13 B-pipe reverted) with 512 THREADS / 8 WAVES per block. Occupancy was
// pinned at 4 waves/CU (10.5%) in every prior round and multi-block residency
// failed (r12); doubling waves-per-block doubles per-CU TLP without depending
// on co-residency. 14 m-tiles split 4/4/3/3 over 4 m-groups x 2 k-groups; all
// addressing formulas byte-identical to the r8-verified mapping. ----
__global__ __launch_bounds__(512) void conv_mfma(const unsigned short* __restrict__ xq8,
                                                 const unsigned short* __restrict__ wt,
                                                 const float* __restrict__ bias,
                                                 float* __restrict__ out,
                                                 const unsigned short* __restrict__ zp) {
    __shared__ unsigned short xs[2][3328 * 8];    // 2 x 53,248 B
    const int tid = threadIdx.x;
    const int wave = tid >> 6, lane = tid & 63;
    const int wl = lane & 15, quad = lane >> 4;
    const int kg = wave & 1, mg = wave >> 1;      // mg 0..3
    const int mbase = (mg < 2) ? mg * 4 : 8 + (mg - 2) * 3;
    const int mcnt  = (mg < 2) ? 4 : 3;
    const int bs = blockIdx.x;

    // staging: 52 chunk-groups of 64 lanes (3328 chunks; 3200 real + 128 pad).
    // slot k of wave w covers chunk-group cg = w*7+k; cg>=52 inert.
    unsigned pk7[7];
    #pragma unroll
    for (int k = 0; k < 7; ++k) {
        int cg = wave * 7 + k;
        int g = cg * 64 + lane;
        if (cg < 52 && g < 3200) {
            int oct = g / 400, rem = g - oct * 400;
            int r = rem / 40, pix = rem - r * 40;
            int pixs = pix ^ oct;                 // source-side swizzle (low 3 bits)
            pk7[k] = ((unsigned)r << 24) | (unsigned)(oct * PLANE8 + pixs * 8);
        } else pk7[k] = 0xFF000000u;
    }

    float bv[2];
    #pragma unroll
    for (int j = 0; j < 2; ++j) bv[j] = bias[kg * 32 + j * 16 + wl];
    int pixb[4];
    #pragma unroll
    for (int mti = 0; mti < 4; ++mti) {
        int m = (mbase + mti) * 16 + wl;          // mti >= mcnt never dereferenced
        pixb[mti] = (m / 28) * 40 + (m % 28) + 1;
    }

    auto issue = [&](int ti, int bi) {
        int t = bs + 256 * ti;
        int st = ((t & 7) * 224) + (t >> 3);      // XCD-chunked swizzle
        int n = st / 56, rem = st - n * 56;
        int h0 = (rem >> 2) * 8, w0 = (rem & 3) * 28;
        const unsigned short* base = xq8 + n * 8 * PLANE8 + w0 * 8;
        #pragma unroll
        for (int k = 0; k < 7; ++k) {
            int cg = wave * 7 + k;
            if (cg < 52) {                        // wave-uniform guard
                unsigned pk = pk7[k];
                int r = (int)(pk >> 24);
                int hh = h0 - 1 + r;
                bool ok = (r <= 9) && (hh >= 0) && (hh < HW);
                const unsigned short* src = ok ? (base + (pk & 0xFFFFFFu) + hh * ROWS8) : zp;
                unsigned short* dst = (unsigned short*)&xs[bi][cg * 512];
                __builtin_amdgcn_global_load_lds(
                    (const __attribute__((address_space(1))) void*)src,
                    (__attribute__((address_space(3))) void*)dst, 16, 0, 0);
            }
        }
    };

    issue(0, 0);

    #pragma unroll 1
    for (int i = 0; i < 7; ++i) {
        asm volatile("s_waitcnt vmcnt(0)" ::: "memory");
        __builtin_amdgcn_s_barrier();
        if (i < 6) issue(i + 1, (i + 1) & 1);

        int t = bs + 256 * i;
        int st = ((t & 7) * 224) + (t >> 3);
        int n = st / 56, rem = st - n * 56;
        int h0 = (rem >> 2) * 8, w0 = (rem & 3) * 28;
        const unsigned short* xb = &xs[i & 1][0];

        f32x4 acc[4][2];
        f32x4 zero = {0.f, 0.f, 0.f, 0.f};
        #pragma unroll
        for (int mti = 0; mti < 4; ++mti) { acc[mti][0] = zero; acc[mti][1] = zero; }

        #pragma unroll
        for (int p = 0; p < 9; ++p) {
            const int dpix = (p / 3) * 40 + (p % 3);
            #pragma unroll
            for (int cs = 0; cs < 2; ++cs) {
                const int oq = cs * 4 + quad;
                s16x8 B0 = *(const s16x8*)(wt + p * 4096 + ((kg * 2 + 0) * 16 + wl) * 64 + cs * 32 + quad * 8);
                s16x8 B1 = *(const s16x8*)(wt + p * 4096 + ((kg * 2 + 1) * 16 + wl) * 64 + cs * 32 + quad * 8);
                s16x8 A[4];
                #pragma unroll
                for (int mti = 0; mti < 4; ++mti)
                    if (mti < mcnt) {
                        int pix = pixb[mti] + dpix;
                        A[mti] = *(const s16x8*)(xb + (oq * 400 + (pix ^ oq)) * 8);
                    }
                #pragma unroll
                for (int mti = 0; mti < 4; ++mti)
                    if (mti < mcnt) {
                        acc[mti][0] = __builtin_amdgcn_mfma_f32_16x16x32_bf16(A[mti], B0, acc[mti][0], 0, 0, 0);
                        acc[mti][1] = __builtin_amdgcn_mfma_f32_16x16x32_bf16(A[mti], B1, acc[mti][1], 0, 0, 0);
                    }
            }
        }

        int obase = n * CHW + h0 * HW + w0;
        #pragma unroll
        for (int mti = 0; mti < 4; ++mti)
            if (mti < mcnt) {
                int m0 = (mbase + mti) * 16 + quad * 4;
                int eofs = (m0 / 28) * HW + (m0 % 28);
                #pragma unroll
                for (int j = 0; j < 2; ++j) {
                    f32x4 v = acc[mti][j];
                    v.x += bv[j]; v.y += bv[j]; v.z += bv[j]; v.w += bv[j];
                    *(f32x4*)(out + obase + (kg * 32 + j * 16 + wl) * 12544 + eofs) = v;
                }
            }
    }
}

extern "C" void kernel_launch(void* const* d_in, const int* in_sizes, int n_in,
                              void* d_out, int out_size, void* d_ws, size_t ws_size,
                              hipStream_t stream) {
    const float* x    = (const float*)d_in[0];
    const float* w    = (const float*)d_in[1];
    const float* bias = (const float*)d_in[2];
    float* out = (float*)d_out;
    char* ws = (char*)d_ws;
    unsigned short* xq8 = (unsigned short*)ws;
    unsigned short* wt  = (unsigned short*)(ws + WT_OFF);
    unsigned short* zp  = (unsigned short*)(ws + ZP_OFF);

    hipLaunchKernelGGL(qx_fused,  dim3(7172), dim3(256), 0, stream, x, w, xq8, wt, (u32x4*)zp);
    hipLaunchKernelGGL(conv_mfma, dim3(256),  dim3(512), 0, stream, xq8, wt, bias, out, zp);
}

// Round 15
// 249.837 us; speedup vs baseline: 1.0868x; 1.0868x over previous
//
#include <hip/hip_runtime.h>

typedef __attribute__((ext_vector_type(4))) float f32x4;
typedef __attribute__((ext_vector_type(8))) short s16x8;
typedef __attribute__((ext_vector_type(4))) unsigned int u32x4;

#define HW 112
#define ROWS8 (116*8)             // shorts per (plane,row) = 928 (116 slots x 8c)
#define PLANE8 (112*ROWS8)        // shorts per (n,oct) plane = 103,936
#define CHW (64*112*112)          // 802816
#define X_ELEMS 25690112

// ws byte offsets (conv over-reads <=112B past xq8 -> 4KB slack)
#define WT_OFF    53219328
#define ZP_OFF    59001984

__device__ __forceinline__ unsigned short f32_to_bf16_exact(float q) {
    return (unsigned short)(__float_as_uint(q) >> 16);
}
__device__ __forceinline__ unsigned int pack_bf16x2(float a, float b) {
    return __builtin_amdgcn_perm(__float_as_uint(b), __float_as_uint(a), 0x07060302u);
}
__device__ __forceinline__ void scale_from_max(float m, float& scale, float& inv) {
    if (m > 0.f) {
        int e = (int)((__float_as_uint(m) >> 23) & 0xFF) - 127;
        scale = __builtin_ldexpf(1.0f, e - 7);
        inv   = __builtin_ldexpf(1.0f, 7 - e);
    } else { scale = 0.f; inv = 0.f; }
}

// ---- QX: ONE pass over x. Blocks 7168-7171 run the weight path instead
// (saves a launch); block 7168 also zeroes zp. (r11 configuration, verbatim.) ----
__global__ __launch_bounds__(256) void qx_fused(const float* __restrict__ x,
                                                const float* __restrict__ w,
                                                unsigned short* __restrict__ xq8,
                                                unsigned short* __restrict__ wt,
                                                u32x4* __restrict__ zp) {
    __shared__ float vals[8 * 448];               // f32 values, this chunk, 8 channels
    __shared__ float lmax[1024];                  // 8 ch x 128 grains (112 + 2x8 halo)
    __shared__ float2 ssc[8][16];                 // per-channel group (s, inv)
    __shared__ int sgs[8];                        // per-channel first group id
    const int tid = threadIdx.x;
    const int b = blockIdx.x;

    if (b >= 7168) {                              // ---- weight path: 1024 groups of 36
        if (b == 7168 && tid < 64) zp[tid] = (u32x4){0u, 0u, 0u, 0u};
        int g = (b - 7168) * 256 + tid;
        const float4* p = (const float4*)w + g * 9;
        float vv[36]; float m = 0.f;
        #pragma unroll
        for (int i = 0; i < 9; ++i) {
            float4 v = p[i];
            vv[i*4+0]=v.x; vv[i*4+1]=v.y; vv[i*4+2]=v.z; vv[i*4+3]=v.w;
            m = fmaxf(m, fmaxf(fmaxf(fabsf(v.x), fabsf(v.y)), fmaxf(fabsf(v.z), fabsf(v.w))));
        }
        float s, inv; scale_from_max(m, s, inv);
        #pragma unroll
        for (int j = 0; j < 36; ++j) {
            int flat = g * 36 + j;
            int k = flat / 576, rem = flat % 576;
            int c = rem / 9, pp = rem % 9;
            float q = rintf(vv[j] * inv) * s;
            wt[pp * 4096 + k * 64 + c] = f32_to_bf16_exact(q);
        }
        return;
    }

    const int plane = b / 28, chunk = b - plane * 28;
    const int p0 = chunk * 448;
    const int base_plane = plane * 8 * 12544;     // flat base of channel oct*8 of image n

    #pragma unroll
    for (int it = 0; it < 4; ++it) {
        int g = it * 256 + tid;
        int j = g >> 7, gi = g & 127;
        int flat = base_plane + j * 12544 + p0 - 32 + gi * 4;
        float4 v = {0.f, 0.f, 0.f, 0.f};
        if (flat >= 0 && flat < X_ELEMS) v = *(const float4*)(x + flat);  // 16B aligned
        lmax[g] = fmaxf(fmaxf(fabsf(v.x), fabsf(v.y)), fmaxf(fabsf(v.z), fabsf(v.w)));
        if (gi >= 8 && gi < 120)
            *(f32x4*)&vals[j * 448 + (gi - 8) * 4] = (f32x4){v.x, v.y, v.z, v.w};
    }
    __syncthreads();

    if (tid < 128) {
        int j = tid >> 4, k = tid & 15;
        unsigned a0 = (unsigned)(base_plane + j * 12544 + p0);
        int gstart = (int)(a0 / 36u);
        int gend   = (int)((a0 + 447u) / 36u);
        if (k == 0) sgs[j] = gstart;
        if (gstart + k <= gend) {
            int ps = 36 * (gstart + k) - (int)a0;  // group start rel. p0, in [-32, 444], 4-aligned
            int gb = ps / 4 + 8;                   // first grain index in lmax[j][.]
            float m = 0.f;
            #pragma unroll
            for (int q = 0; q < 9; ++q) m = fmaxf(m, lmax[j * 128 + gb + q]);
            float s, inv; scale_from_max(m, s, inv);
            ssc[j][k] = make_float2(s, inv);
        }
    }
    __syncthreads();

    const int hrow0 = chunk * 4;
    #pragma unroll
    for (int it = 0; it < 2; ++it) {
        int s = it * 256 + tid;
        if (s < 464) {                            // 4 rows x 116 slots (incl. pads)
            int h = s / 116, w2 = s - h * 116;
            unsigned short* dst = xq8 + (plane * 112 + hrow0 + h) * ROWS8 + w2 * 8;
            u32x4 o = {0u, 0u, 0u, 0u};
            if (w2 >= 2 && w2 < 114) {
                int dp = h * 112 + (w2 - 2);
                unsigned pbase = (unsigned)(base_plane + p0 + dp);
                float qv[8];
                #pragma unroll
                for (int j = 0; j < 8; ++j) {
                    float v = vals[j * 448 + dp];
                    unsigned g = (pbase + (unsigned)j * 12544u) / 36u;
                    float2 sv = ssc[j][(int)g - sgs[j]];
                    qv[j] = rintf(v * sv.y) * sv.x;
                }
                o.x = pack_bf16x2(qv[0], qv[1]);
                o.y = pack_bf16x2(qv[2], qv[3]);
                o.z = pack_bf16x2(qv[4], qv[5]);
                o.w = pack_bf16x2(qv[6], qv[7]);
            }
            *(u32x4*)dst = o;                     // coalesced 16B/lane
        }
    }
}

// ---- conv: r11 configuration, verbatim — the session's wall-time best
// (250.1us). Persistent grid 256, dbuf LDS, 52x global_load_lds_dwordx4 with
// source-side pix^oct swizzle, counted vmcnt(14) (all but the newest 14 ops =
// the output stores), zero page for OOB rows. ----
__global__ __launch_bounds__(256) void conv_mfma(const unsigned short* __restrict__ xq8,
                                                 const unsigned short* __restrict__ wt,
                                                 const float* __restrict__ bias,
                                                 float* __restrict__ out,
                                                 const unsigned short* __restrict__ zp) {
    __shared__ unsigned short xs[2][3328 * 8];    // 2 x 53,248 B
    const int tid = threadIdx.x;
    const int wave = tid >> 6, lane = tid & 63;
    const int wl = lane & 15, quad = lane >> 4;
    const int kg = wave & 1, mg = wave >> 1;
    const int bs = blockIdx.x;

    unsigned pk13[13];
    #pragma unroll
    for (int k = 0; k < 13; ++k) {
        int g = (wave * 13 + k) * 64 + lane;
        if (g < 3200) {
            int oct = g / 400, rem = g - oct * 400;
            int r = rem / 40, pix = rem - r * 40;
            int pixs = pix ^ oct;
            pk13[k] = ((unsigned)r << 24) | (unsigned)(oct * PLANE8 + pixs * 8);
        } else pk13[k] = 0xFF000000u;
    }

    float bv[2];
    #pragma unroll
    for (int j = 0; j < 2; ++j) bv[j] = bias[kg * 32 + j * 16 + wl];
    int pixb[7];
    #pragma unroll
    for (int mti = 0; mti < 7; ++mti) {
        int m = (mg * 7 + mti) * 16 + wl;
        pixb[mti] = (m / 28) * 40 + (m % 28) + 1;
    }

    auto issue = [&](int ti, int bi) {
        int t = bs + 256 * ti;
        int st = ((t & 7) * 224) + (t >> 3);
        int n = st / 56, rem = st - n * 56;
        int h0 = (rem >> 2) * 8, w0 = (rem & 3) * 28;
        const unsigned short* base = xq8 + n * 8 * PLANE8 + w0 * 8;
        #pragma unroll
        for (int k = 0; k < 13; ++k) {
            unsigned pk = pk13[k];
            int r = (int)(pk >> 24);
            int hh = h0 - 1 + r;
            bool ok = (r <= 9) && (hh >= 0) && (hh < HW);
            const unsigned short* src = ok ? (base + (pk & 0xFFFFFFu) + hh * ROWS8) : zp;
            unsigned short* dst = (unsigned short*)&xs[bi][(wave * 13 + k) * 512];
            __builtin_amdgcn_global_load_lds(
                (const __attribute__((address_space(1))) void*)src,
                (__attribute__((address_space(3))) void*)dst, 16, 0, 0);
        }
    };

    issue(0, 0);

    #pragma unroll 1
    for (int i = 0; i < 7; ++i) {
        if (i == 0) asm volatile("s_waitcnt vmcnt(0)" ::: "memory");
        else        asm volatile("s_waitcnt vmcnt(14)" ::: "memory");  // all but newest 14 (stores)
        __builtin_amdgcn_s_barrier();
        if (i < 6) issue(i + 1, (i + 1) & 1);

        int t = bs + 256 * i;
        int st = ((t & 7) * 224) + (t >> 3);
        int n = st / 56, rem = st - n * 56;
        int h0 = (rem >> 2) * 8, w0 = (rem & 3) * 28;
        const unsigned short* xb = &xs[i & 1][0];

        f32x4 acc[7][2];
        f32x4 zero = {0.f, 0.f, 0.f, 0.f};
        #pragma unroll
        for (int mti = 0; mti < 7; ++mti) { acc[mti][0] = zero; acc[mti][1] = zero; }

        #pragma unroll
        for (int p = 0; p < 9; ++p) {
            const int dpix = (p / 3) * 40 + (p % 3);
            #pragma unroll
            for (int cs = 0; cs < 2; ++cs) {
                const int oq = cs * 4 + quad;
                s16x8 B0 = *(const s16x8*)(wt + p * 4096 + ((kg * 2 + 0) * 16 + wl) * 64 + cs * 32 + quad * 8);
                s16x8 B1 = *(const s16x8*)(wt + p * 4096 + ((kg * 2 + 1) * 16 + wl) * 64 + cs * 32 + quad * 8);
                s16x8 A[7];
                #pragma unroll
                for (int mti = 0; mti < 7; ++mti) {
                    int pix = pixb[mti] + dpix;
                    A[mti] = *(const s16x8*)(xb + (oq * 400 + (pix ^ oq)) * 8);
                }
                #pragma unroll
                for (int mti = 0; mti < 7; ++mti) {
                    acc[mti][0] = __builtin_amdgcn_mfma_f32_16x16x32_bf16(A[mti], B0, acc[mti][0], 0, 0, 0);
                    acc[mti][1] = __builtin_amdgcn_mfma_f32_16x16x32_bf16(A[mti], B1, acc[mti][1], 0, 0, 0);
                }
            }
        }

        int obase = n * CHW + h0 * HW + w0;
        #pragma unroll
        for (int mti = 0; mti < 7; ++mti) {
            int m0 = (mg * 7 + mti) * 16 + quad * 4;
            int eofs = (m0 / 28) * HW + (m0 % 28);
            #pragma unroll
            for (int j = 0; j < 2; ++j) {
                f32x4 v = acc[mti][j];
                v.x += bv[j]; v.y += bv[j]; v.z += bv[j]; v.w += bv[j];
                *(f32x4*)(out + obase + (kg * 32 + j * 16 + wl) * 12544 + eofs) = v;
            }
        }
    }
}

extern "C" void kernel_launch(void* const* d_in, const int* in_sizes, int n_in,
                              void* d_out, int out_size, void* d_ws, size_t ws_size,
                              hipStream_t stream) {
    const float* x    = (const float*)d_in[0];
    const float* w    = (const float*)d_in[1];
    const float* bias = (const float*)d_in[2];
    float* out = (float*)d_out;
    char* ws = (char*)d_ws;
    unsigned short* xq8 = (unsigned short*)ws;
    unsigned short* wt  = (unsigned short*)(ws + WT_OFF);
    unsigned short* zp  = (unsigned short*)(ws + ZP_OFF);

    hipLaunchKernelGGL(qx_fused,  dim3(7172), dim3(256), 0, stream, x, w, xq8, wt, (u32x4*)zp);
    hipLaunchKernelGGL(conv_mfma, dim3(256),  dim3(256), 0, stream, xq8, wt, bias, out, zp);
}